// Round 2
// baseline (256.193 us; speedup 1.0000x reference)
//
#include <hip/hip_runtime.h>

namespace {

constexpr int H = 224, W = 224, B = 4, S = 21, R = 5;
constexpr int HW = H * W;            // 50176 = 196 * 256, exact grid

__constant__ float c_sin[5] = {-0.5000010604f, -0.2588196365f, 0.0f,
                                0.2588196365f,  0.5000010604f};
__constant__ float c_cos[5] = { 0.8660247916f,  0.9659256678f, 1.0f,
                                0.9659256678f,  0.8660247916f};

struct alignas(4) f3 { float x, y, z; };   // 12 B, merges to dwordx3

__device__ __forceinline__ float vIn(int x) {   // H == W
    return ((unsigned)x < (unsigned)W) ? 1.0f : 0.0f;
}
__device__ __forceinline__ int clampW(int x) {
    return min(max(x, 0), W - 1);
}

// Shared rotation geometry (identical math to the proven fused kernel).
struct Geo {
    int x0, y0;
    float wx, wy, wxl, wyl;
    float vx0, vx1, vy0, vy1;
    float rwy0, rwy1, cwx0, cwx1;
};

__device__ __forceinline__ Geo make_geo(int pix, int r) {
    int h = pix / W;
    int w = pix - h * W;
    float sr = c_sin[r], cr = c_cos[r];
    const float cx = 0.5f * (W - 1);
    float dx = (float)w - cx;
    float dy = (float)h - cx;
    // Stage-2 rotated source coordinate (align_corners=True, H == W).
    float ix = fmaf(dy, sr, fmaf(dx, cr, cx));
    float iy = fmaf(dy, cr, fmaf(-dx, sr, cx));

    Geo g;
    float x0f = floorf(ix), y0f = floorf(iy);
    g.x0 = (int)x0f; g.y0 = (int)y0f;
    g.wx = ix - x0f; g.wy = iy - y0f;
    g.wxl = 1.0f - g.wx; g.wyl = 1.0f - g.wy;
    g.vx0 = vIn(g.x0); g.vx1 = vIn(g.x0 + 1);
    g.vy0 = vIn(g.y0); g.vy1 = vIn(g.y0 + 1);
    g.rwy0 = g.wyl * g.vy0; g.rwy1 = g.wy * g.vy1;   // stage-2 y weights
    g.cwx0 = g.wxl * g.vx0; g.cwx1 = g.wx * g.vx1;   // stage-2 x weights
    return g;
}

// ---- x-shift group (s = 10..20): taps in rows {y0, y0+1}, cols x0-3..x0+4
// Register tile: 48 floats (vs 96 in the fused kernel) -> ~2x occupancy.
__global__ __launch_bounds__(256, 4) void shift_rotate_x(
    const float* __restrict__ xs, float* __restrict__ out) {
    int pix = blockIdx.x * 256 + threadIdx.x;     // 196*256 == HW, no tail
    int b = blockIdx.y;
    int r = blockIdx.z;
    Geo g = make_geo(pix, r);

    const float* img = xs + (size_t)b * (HW * 3);
    size_t obase = ((size_t)(r * S) * B + b) * (size_t)(HW * 3) + (size_t)pix * 3;
    constexpr size_t splane = (size_t)B * HW * 3;   // +1 in s

    float Hb[2][8][3];
    const float* r0 = img + clampW(g.y0) * (W * 3);
    const float* r1 = img + clampW(g.y0 + 1) * (W * 3);
    #pragma unroll
    for (int j = 0; j < 8; ++j) {
        int xc = clampW(g.x0 - 3 + j) * 3;
        const f3 t0 = *(const f3*)(r0 + xc);
        const f3 t1 = *(const f3*)(r1 + xc);
        Hb[0][j][0] = t0.x; Hb[0][j][1] = t0.y; Hb[0][j][2] = t0.z;
        Hb[1][j][0] = t1.x; Hb[1][j][1] = t1.y; Hb[1][j][2] = t1.z;
    }
    constexpr int tx_tab[11] = {1, 2, 3, 4, 5, -1, -2, -3, -4, -5, 0};
    #pragma unroll
    for (int k = 0; k < 11; ++k) {
        const int tx = tx_tab[k];
        const int s = 10 + k;
        float a[3];
        if (tx & 1) {
            const int j = ((tx - 1) >> 1) + 3;       // compile-time
            int xb = g.x0 + ((tx - 1) >> 1);
            float cw0 = 0.5f * g.wxl * g.vx0 * vIn(xb);
            float cw1 = 0.5f * (g.wxl * g.vx0 + g.wx * g.vx1) * vIn(xb + 1);
            float cw2 = 0.5f * g.wx * g.vx1 * vIn(xb + 2);
            #pragma unroll
            for (int c = 0; c < 3; ++c)
                a[c] = g.rwy0 * (cw0 * Hb[0][j][c] + cw1 * Hb[0][j + 1][c] + cw2 * Hb[0][j + 2][c])
                     + g.rwy1 * (cw0 * Hb[1][j][c] + cw1 * Hb[1][j + 1][c] + cw2 * Hb[1][j + 2][c]);
        } else {
            const int sx = tx >> 1;
            const int j = sx + 3;                    // compile-time
            float ax0 = g.cwx0 * vIn(g.x0 + sx);
            float ax1 = g.cwx1 * vIn(g.x0 + 1 + sx);
            #pragma unroll
            for (int c = 0; c < 3; ++c)
                a[c] = g.rwy0 * (ax0 * Hb[0][j][c] + ax1 * Hb[0][j + 1][c])
                     + g.rwy1 * (ax0 * Hb[1][j][c] + ax1 * Hb[1][j + 1][c]);
        }
        f3* op = (f3*)(out + obase + (size_t)s * splane);
        f3 v; v.x = a[0]; v.y = a[1]; v.z = a[2];
        *op = v;
    }
}

// ---- y-shift group (s = 0..9): taps in cols {x0, x0+1}, rows y0-3..y0+4
__global__ __launch_bounds__(256, 4) void shift_rotate_y(
    const float* __restrict__ xs, float* __restrict__ out) {
    int pix = blockIdx.x * 256 + threadIdx.x;
    int b = blockIdx.y;
    int r = blockIdx.z;
    Geo g = make_geo(pix, r);

    const float* img = xs + (size_t)b * (HW * 3);
    size_t obase = ((size_t)(r * S) * B + b) * (size_t)(HW * 3) + (size_t)pix * 3;
    constexpr size_t splane = (size_t)B * HW * 3;

    float Vb[8][2][3];
    int xc0 = clampW(g.x0) * 3, xc1 = clampW(g.x0 + 1) * 3;
    #pragma unroll
    for (int i = 0; i < 8; ++i) {
        const float* rr = img + clampW(g.y0 - 3 + i) * (W * 3);
        const f3 t0 = *(const f3*)(rr + xc0);
        const f3 t1 = *(const f3*)(rr + xc1);
        Vb[i][0][0] = t0.x; Vb[i][0][1] = t0.y; Vb[i][0][2] = t0.z;
        Vb[i][1][0] = t1.x; Vb[i][1][1] = t1.y; Vb[i][1][2] = t1.z;
    }
    constexpr int ty_tab[10] = {1, 2, 3, 4, 5, -1, -2, -3, -4, -5};
    #pragma unroll
    for (int k = 0; k < 10; ++k) {
        const int ty = ty_tab[k];
        const int s = k;
        float a[3];
        if (ty & 1) {
            const int i = ((ty - 1) >> 1) + 3;       // compile-time
            int yb = g.y0 + ((ty - 1) >> 1);
            float rw0 = 0.5f * g.wyl * g.vy0 * vIn(yb);
            float rw1 = 0.5f * (g.wyl * g.vy0 + g.wy * g.vy1) * vIn(yb + 1);
            float rw2 = 0.5f * g.wy * g.vy1 * vIn(yb + 2);
            #pragma unroll
            for (int c = 0; c < 3; ++c)
                a[c] = g.cwx0 * (rw0 * Vb[i][0][c] + rw1 * Vb[i + 1][0][c] + rw2 * Vb[i + 2][0][c])
                     + g.cwx1 * (rw0 * Vb[i][1][c] + rw1 * Vb[i + 1][1][c] + rw2 * Vb[i + 2][1][c]);
        } else {
            const int sy = ty >> 1;
            const int i = sy + 3;                    // compile-time
            float ay0 = g.rwy0 * vIn(g.y0 + sy);
            float ay1 = g.rwy1 * vIn(g.y0 + 1 + sy);
            #pragma unroll
            for (int c = 0; c < 3; ++c)
                a[c] = g.cwx0 * (ay0 * Vb[i][0][c] + ay1 * Vb[i + 1][0][c])
                     + g.cwx1 * (ay0 * Vb[i][1][c] + ay1 * Vb[i + 1][1][c]);
        }
        f3* op = (f3*)(out + obase + (size_t)s * splane);
        f3 v; v.x = a[0]; v.y = a[1]; v.z = a[2];
        *op = v;
    }
}

} // namespace

extern "C" void kernel_launch(void* const* d_in, const int* in_sizes, int n_in,
                              void* d_out, int out_size, void* d_ws, size_t ws_size,
                              hipStream_t stream) {
    const float* xs = (const float*)d_in[0];
    float* out = (float*)d_out;
    dim3 grid(HW / 256, B, R);
    shift_rotate_x<<<grid, dim3(256), 0, stream>>>(xs, out);
    shift_rotate_y<<<grid, dim3(256), 0, stream>>>(xs, out);
}

// Round 3
// 243.345 us; speedup vs baseline: 1.0528x; 1.0528x over previous
//
#include <hip/hip_runtime.h>

namespace {

constexpr int H = 224, W = 224, B = 4, S = 21, R = 5;
constexpr int HW = H * W;            // 50176

constexpr int TW = 32, TH = 8;       // output tile per block (256 threads)
constexpr int GX = W / TW;           // 7
constexpr int GY = H / TH;           // 28
constexpr int WINW = 40, WINH = 32;  // staged source window
                                     // fit proof: col span <= 31*cos+7*|sin| <= 31.75 -> +8 halo <= 40
                                     //            row span <= 31*|sin|+7*cos <= 21.6  -> +8 halo <= 31
constexpr int LROW = WINW * 3;       // 120 floats per window row
constexpr int LSIZE = WINH * LROW;   // 3840 floats = 15360 B LDS

__constant__ float c_sin[5] = {-0.5000010604f, -0.2588196365f, 0.0f,
                                0.2588196365f,  0.5000010604f};
__constant__ float c_cos[5] = { 0.8660247916f,  0.9659256678f, 1.0f,
                                0.9659256678f,  0.8660247916f};

struct alignas(4) f3 { float x, y, z; };   // 12 B

__device__ __forceinline__ float vIn(int x) {   // H == W
    return ((unsigned)x < (unsigned)W) ? 1.0f : 0.0f;
}

// One block = 32x8 output tile for fixed (b, r); all 21 shifts from LDS window.
__global__ __launch_bounds__(256) void fused_shift_rotate_lds(
    const float* __restrict__ xs, float* __restrict__ out) {
    __shared__ float lds[LSIZE];
    const int tid = threadIdx.x;
    const int tile = blockIdx.x;
    const int tx0 = (tile % GX) * TW;
    const int ty0 = (tile / GX) * TH;
    const int b = blockIdx.y;
    const int r = blockIdx.z;

    const float sr = c_sin[r], cr = c_cos[r];
    const float cx = 0.5f * (W - 1);

    // ---- uniform source-window origin from tile-corner extremes
    const float dxs = (float)tx0 - cx, dxe = (float)(tx0 + TW - 1) - cx;
    const float dys = (float)ty0 - cx, dye = (float)(ty0 + TH - 1) - cx;
    // ix = cx + dx*cr + dy*sr ; iy = cx - dx*sr + dy*cr  (cr > 0 always)
    const float ixmin = cx + dxs * cr + fminf(dys * sr, dye * sr);
    const float iymin = cx + fminf(-dxs * sr, -dxe * sr) + dys * cr;
    const int cmin = min(max((int)floorf(ixmin) - 3, 0), W - WINW);
    const int rmin = min(max((int)floorf(iymin) - 3, 0), H - WINH);

    // ---- stage window: coalesced stride-1 global reads, stride-1 ds_write
    const float* img = xs + (size_t)b * (HW * 3);
    const float* gsrc = img + rmin * (W * 3) + cmin * 3;
    #pragma unroll
    for (int k = 0; k < LSIZE / 256; ++k) {   // 15 iterations
        int idx = tid + k * 256;
        int row = idx / LROW;                 // magic-mul
        int f = idx - row * LROW;
        lds[idx] = gsrc[row * (W * 3) + f];
    }
    __syncthreads();

    // ---- per-thread rotation geometry (identical math to proven kernel)
    const int wpx = tx0 + (tid & (TW - 1));
    const int hpx = ty0 + (tid >> 5);
    const float dx = (float)wpx - cx;
    const float dy = (float)hpx - cx;
    const float ix = fmaf(dy, sr, fmaf(dx, cr, cx));
    const float iy = fmaf(dy, cr, fmaf(-dx, sr, cx));

    const float x0f = floorf(ix), y0f = floorf(iy);
    const int x0 = (int)x0f, y0 = (int)y0f;
    const float wx = ix - x0f, wy = iy - y0f;
    const float wxl = 1.0f - wx, wyl = 1.0f - wy;

    const float vx0 = vIn(x0), vx1 = vIn(x0 + 1);
    const float vy0 = vIn(y0), vy1 = vIn(y0 + 1);
    const float rwy0 = wyl * vy0, rwy1 = wy * vy1;   // stage-2 y weights
    const float cwx0 = wxl * vx0, cwx1 = wx * vx1;   // stage-2 x weights

    const int pix = hpx * W + wpx;
    size_t obase = ((size_t)(r * S) * B + b) * (size_t)(HW * 3) + (size_t)pix * 3;
    constexpr size_t splane = (size_t)B * HW * 3;    // +1 in s

    // window-local clamped coords; == clampW(g) - origin by the fit proof
    // (any tap with nonzero weight is in-window; zero-weight taps may read
    //  any in-window value)
    auto lcol = [&](int g) { int l = g - cmin; return min(max(l, 0), WINW - 1); };
    auto lrow = [&](int g) { int l = g - rmin; return min(max(l, 0), WINH - 1); };

    // ---- x-shift group (s = 10..20): rows {y0, y0+1}, cols x0-3..x0+4
    {
        float Hb[2][8][3];
        const float* R0 = &lds[lrow(y0) * LROW];
        const float* R1 = &lds[lrow(y0 + 1) * LROW];
        #pragma unroll
        for (int j = 0; j < 8; ++j) {
            int xc = lcol(x0 - 3 + j) * 3;
            const f3 t0 = *(const f3*)(R0 + xc);
            const f3 t1 = *(const f3*)(R1 + xc);
            Hb[0][j][0] = t0.x; Hb[0][j][1] = t0.y; Hb[0][j][2] = t0.z;
            Hb[1][j][0] = t1.x; Hb[1][j][1] = t1.y; Hb[1][j][2] = t1.z;
        }
        constexpr int tx_tab[11] = {1, 2, 3, 4, 5, -1, -2, -3, -4, -5, 0};
        #pragma unroll
        for (int k = 0; k < 11; ++k) {
            const int tx = tx_tab[k];
            const int s = 10 + k;
            float a[3];
            if (tx & 1) {
                const int j = ((tx - 1) >> 1) + 3;       // compile-time
                int xb = x0 + ((tx - 1) >> 1);
                float cw0 = 0.5f * wxl * vx0 * vIn(xb);
                float cw1 = 0.5f * (wxl * vx0 + wx * vx1) * vIn(xb + 1);
                float cw2 = 0.5f * wx * vx1 * vIn(xb + 2);
                #pragma unroll
                for (int c = 0; c < 3; ++c)
                    a[c] = rwy0 * (cw0 * Hb[0][j][c] + cw1 * Hb[0][j + 1][c] + cw2 * Hb[0][j + 2][c])
                         + rwy1 * (cw0 * Hb[1][j][c] + cw1 * Hb[1][j + 1][c] + cw2 * Hb[1][j + 2][c]);
            } else {
                const int sx = tx >> 1;
                const int j = sx + 3;                    // compile-time
                float ax0 = cwx0 * vIn(x0 + sx);
                float ax1 = cwx1 * vIn(x0 + 1 + sx);
                #pragma unroll
                for (int c = 0; c < 3; ++c)
                    a[c] = rwy0 * (ax0 * Hb[0][j][c] + ax1 * Hb[0][j + 1][c])
                         + rwy1 * (ax0 * Hb[1][j][c] + ax1 * Hb[1][j + 1][c]);
            }
            f3* op = (f3*)(out + obase + (size_t)s * splane);
            f3 v; v.x = a[0]; v.y = a[1]; v.z = a[2];
            *op = v;
        }
    }

    // ---- y-shift group (s = 0..9): cols {x0, x0+1}, rows y0-3..y0+4
    {
        float Vb[8][2][3];
        int xc0 = lcol(x0) * 3, xc1 = lcol(x0 + 1) * 3;
        #pragma unroll
        for (int i = 0; i < 8; ++i) {
            const float* RR = &lds[lrow(y0 - 3 + i) * LROW];
            const f3 t0 = *(const f3*)(RR + xc0);
            const f3 t1 = *(const f3*)(RR + xc1);
            Vb[i][0][0] = t0.x; Vb[i][0][1] = t0.y; Vb[i][0][2] = t0.z;
            Vb[i][1][0] = t1.x; Vb[i][1][1] = t1.y; Vb[i][1][2] = t1.z;
        }
        constexpr int ty_tab[10] = {1, 2, 3, 4, 5, -1, -2, -3, -4, -5};
        #pragma unroll
        for (int k = 0; k < 10; ++k) {
            const int ty = ty_tab[k];
            const int s = k;
            float a[3];
            if (ty & 1) {
                const int i = ((ty - 1) >> 1) + 3;       // compile-time
                int yb = y0 + ((ty - 1) >> 1);
                float rw0 = 0.5f * wyl * vy0 * vIn(yb);
                float rw1 = 0.5f * (wyl * vy0 + wy * vy1) * vIn(yb + 1);
                float rw2 = 0.5f * wy * vy1 * vIn(yb + 2);
                #pragma unroll
                for (int c = 0; c < 3; ++c)
                    a[c] = cwx0 * (rw0 * Vb[i][0][c] + rw1 * Vb[i + 1][0][c] + rw2 * Vb[i + 2][0][c])
                         + cwx1 * (rw0 * Vb[i][1][c] + rw1 * Vb[i + 1][1][c] + rw2 * Vb[i + 2][1][c]);
            } else {
                const int sy = ty >> 1;
                const int i = sy + 3;                    // compile-time
                float ay0 = rwy0 * vIn(y0 + sy);
                float ay1 = rwy1 * vIn(y0 + 1 + sy);
                #pragma unroll
                for (int c = 0; c < 3; ++c)
                    a[c] = cwx0 * (ay0 * Vb[i][0][c] + ay1 * Vb[i + 1][0][c])
                         + cwx1 * (ay0 * Vb[i][1][c] + ay1 * Vb[i + 1][1][c]);
            }
            f3* op = (f3*)(out + obase + (size_t)s * splane);
            f3 v; v.x = a[0]; v.y = a[1]; v.z = a[2];
            *op = v;
        }
    }
}

} // namespace

extern "C" void kernel_launch(void* const* d_in, const int* in_sizes, int n_in,
                              void* d_out, int out_size, void* d_ws, size_t ws_size,
                              hipStream_t stream) {
    const float* xs = (const float*)d_in[0];
    float* out = (float*)d_out;
    dim3 grid(GX * GY, B, R);
    fused_shift_rotate_lds<<<grid, dim3(256), 0, stream>>>(xs, out);
}

// Round 4
// 242.966 us; speedup vs baseline: 1.0544x; 1.0016x over previous
//
#include <hip/hip_runtime.h>

namespace {

constexpr int H = 224, W = 224, B = 4, S = 21, R = 5;
constexpr int HW = H * W;            // 50176

constexpr int TW = 32, TH = 8;       // output tile per block (256 threads)
constexpr int GX = W / TW;           // 7
constexpr int GY = H / TH;           // 28
constexpr int WINW = 40, WINH = 32;  // staged source window
                                     // fit proof: col span <= 31*cos+7*|sin| <= 31.75 -> +8 halo <= 40
                                     //            row span <= 31*|sin|+7*cos <= 21.6  -> +8 halo <= 31
constexpr int LSTR = 41;             // float4 row stride: 41*4=164 dwords == 4 (mod 32), no bank resonance
constexpr int NPX = WINW * WINH;     // 1280 staged pixels; LDS = 32*41*16 B = 20.5 KiB

__constant__ float c_sin[5] = {-0.5000010604f, -0.2588196365f, 0.0f,
                                0.2588196365f,  0.5000010604f};
__constant__ float c_cos[5] = { 0.8660247916f,  0.9659256678f, 1.0f,
                                0.9659256678f,  0.8660247916f};

struct alignas(4) f3 { float x, y, z; };   // 12 B global-side pixel

__device__ __forceinline__ float vIn(int x) {   // H == W
    return ((unsigned)x < (unsigned)W) ? 1.0f : 0.0f;
}
__device__ __forceinline__ float cmp(const float4& v, int c) {  // constant-folded under unroll
    return c == 0 ? v.x : (c == 1 ? v.y : v.z);
}

// One block = 32x8 output tile for fixed (b, r); all 21 shifts from a float4 LDS window.
__global__ __launch_bounds__(256) void fused_shift_rotate_lds4(
    const float* __restrict__ xs, float* __restrict__ out) {
    __shared__ float4 lds4[WINH][LSTR];
    const int tid = threadIdx.x;
    const int tile = blockIdx.x;
    const int tx0 = (tile % GX) * TW;
    const int ty0 = (tile / GX) * TH;
    const int b = blockIdx.y;
    const int r = blockIdx.z;

    const float sr = c_sin[r], cr = c_cos[r];
    const float cx = 0.5f * (W - 1);

    // ---- uniform source-window origin from tile-corner extremes
    const float dxs = (float)tx0 - cx, dxe = (float)(tx0 + TW - 1) - cx;
    const float dys = (float)ty0 - cx, dye = (float)(ty0 + TH - 1) - cx;
    // ix = cx + dx*cr + dy*sr ; iy = cx - dx*sr + dy*cr  (cr > 0 always)
    const float ixmin = cx + dxs * cr + fminf(dys * sr, dye * sr);
    const float iymin = cx + fminf(-dxs * sr, -dxe * sr) + dys * cr;
    const int cmin = min(max((int)floorf(ixmin) - 3, 0), W - WINW);
    const int rmin = min(max((int)floorf(iymin) - 3, 0), H - WINH);

    // ---- stage window: coalesced f3 global reads -> one ds_write_b128 per pixel
    const float* img = xs + (size_t)b * (HW * 3);
    const float* gsrc = img + rmin * (W * 3) + cmin * 3;
    #pragma unroll
    for (int k = 0; k < NPX / 256; ++k) {   // 5 iterations
        int idx = tid + k * 256;
        int row = idx / WINW;               // magic-mul
        int col = idx - row * WINW;
        const f3 t = *(const f3*)(gsrc + row * (W * 3) + col * 3);
        lds4[row][col] = make_float4(t.x, t.y, t.z, 0.0f);
    }
    __syncthreads();

    // ---- per-thread rotation geometry (identical math to proven kernel)
    const int wpx = tx0 + (tid & (TW - 1));
    const int hpx = ty0 + (tid >> 5);
    const float dx = (float)wpx - cx;
    const float dy = (float)hpx - cx;
    const float ix = fmaf(dy, sr, fmaf(dx, cr, cx));
    const float iy = fmaf(dy, cr, fmaf(-dx, sr, cx));

    const float x0f = floorf(ix), y0f = floorf(iy);
    const int x0 = (int)x0f, y0 = (int)y0f;
    const float wx = ix - x0f, wy = iy - y0f;
    const float wxl = 1.0f - wx, wyl = 1.0f - wy;

    const float vx0 = vIn(x0), vx1 = vIn(x0 + 1);
    const float vy0 = vIn(y0), vy1 = vIn(y0 + 1);
    const float rwy0 = wyl * vy0, rwy1 = wy * vy1;   // stage-2 y weights
    const float cwx0 = wxl * vx0, cwx1 = wx * vx1;   // stage-2 x weights

    const int pix = hpx * W + wpx;
    size_t obase = ((size_t)(r * S) * B + b) * (size_t)(HW * 3) + (size_t)pix * 3;
    constexpr size_t splane = (size_t)B * HW * 3;    // +1 in s

    // window-local clamped coords; == clampW(g) - origin by the fit proof
    // (any nonzero-weight tap is in-window; zero-weight taps may read anything in-window)
    auto lcol = [&](int g) { int l = g - cmin; return min(max(l, 0), WINW - 1); };
    auto lrow = [&](int g) { int l = g - rmin; return min(max(l, 0), WINH - 1); };

    const int xc0 = lcol(x0), xc1 = lcol(x0 + 1);

    // ---- x-shift group (s = 10..20): rows {y0, y0+1}, cols x0-3..x0+4
    float4 Hq[2][8];
    {
        const int R0 = lrow(y0), R1 = lrow(y0 + 1);
        #pragma unroll
        for (int j = 0; j < 8; ++j) {
            int xc = lcol(x0 - 3 + j);
            Hq[0][j] = lds4[R0][xc];
            Hq[1][j] = lds4[R1][xc];
        }
    }
    {
        constexpr int tx_tab[11] = {1, 2, 3, 4, 5, -1, -2, -3, -4, -5, 0};
        #pragma unroll
        for (int k = 0; k < 11; ++k) {
            const int tx = tx_tab[k];
            const int s = 10 + k;
            float a[3];
            if (tx & 1) {
                const int j = ((tx - 1) >> 1) + 3;       // compile-time
                int xb = x0 + ((tx - 1) >> 1);
                float cw0 = 0.5f * wxl * vx0 * vIn(xb);
                float cw1 = 0.5f * (wxl * vx0 + wx * vx1) * vIn(xb + 1);
                float cw2 = 0.5f * wx * vx1 * vIn(xb + 2);
                #pragma unroll
                for (int c = 0; c < 3; ++c)
                    a[c] = rwy0 * (cw0 * cmp(Hq[0][j], c) + cw1 * cmp(Hq[0][j + 1], c) + cw2 * cmp(Hq[0][j + 2], c))
                         + rwy1 * (cw0 * cmp(Hq[1][j], c) + cw1 * cmp(Hq[1][j + 1], c) + cw2 * cmp(Hq[1][j + 2], c));
            } else {
                const int sx = tx >> 1;
                const int j = sx + 3;                    // compile-time
                float ax0 = cwx0 * vIn(x0 + sx);
                float ax1 = cwx1 * vIn(x0 + 1 + sx);
                #pragma unroll
                for (int c = 0; c < 3; ++c)
                    a[c] = rwy0 * (ax0 * cmp(Hq[0][j], c) + ax1 * cmp(Hq[0][j + 1], c))
                         + rwy1 * (ax0 * cmp(Hq[1][j], c) + ax1 * cmp(Hq[1][j + 1], c));
            }
            f3* op = (f3*)(out + obase + (size_t)s * splane);
            f3 v; v.x = a[0]; v.y = a[1]; v.z = a[2];
            *op = v;
        }
    }

    // ---- y-shift group (s = 0..9): cols {x0, x0+1}, rows y0-3..y0+4
    // rows i=3,4 overlap Hq (row y0 cols x0,x0+1 and row y0+1 cols x0,x0+1): reuse regs.
    float4 Vq[8][2];
    #pragma unroll
    for (int i = 0; i < 8; ++i) {
        if (i == 3)      { Vq[3][0] = Hq[0][3]; Vq[3][1] = Hq[0][4]; }
        else if (i == 4) { Vq[4][0] = Hq[1][3]; Vq[4][1] = Hq[1][4]; }
        else {
            const int RR = lrow(y0 - 3 + i);
            Vq[i][0] = lds4[RR][xc0];
            Vq[i][1] = lds4[RR][xc1];
        }
    }
    {
        constexpr int ty_tab[10] = {1, 2, 3, 4, 5, -1, -2, -3, -4, -5};
        #pragma unroll
        for (int k = 0; k < 10; ++k) {
            const int ty = ty_tab[k];
            const int s = k;
            float a[3];
            if (ty & 1) {
                const int i = ((ty - 1) >> 1) + 3;       // compile-time
                int yb = y0 + ((ty - 1) >> 1);
                float rw0 = 0.5f * wyl * vy0 * vIn(yb);
                float rw1 = 0.5f * (wyl * vy0 + wy * vy1) * vIn(yb + 1);
                float rw2 = 0.5f * wy * vy1 * vIn(yb + 2);
                #pragma unroll
                for (int c = 0; c < 3; ++c)
                    a[c] = cwx0 * (rw0 * cmp(Vq[i][0], c) + rw1 * cmp(Vq[i + 1][0], c) + rw2 * cmp(Vq[i + 2][0], c))
                         + cwx1 * (rw0 * cmp(Vq[i][1], c) + rw1 * cmp(Vq[i + 1][1], c) + rw2 * cmp(Vq[i + 2][1], c));
            } else {
                const int sy = ty >> 1;
                const int i = sy + 3;                    // compile-time
                float ay0 = rwy0 * vIn(y0 + sy);
                float ay1 = rwy1 * vIn(y0 + 1 + sy);
                #pragma unroll
                for (int c = 0; c < 3; ++c)
                    a[c] = cwx0 * (ay0 * cmp(Vq[i][0], c) + ay1 * cmp(Vq[i + 1][0], c))
                         + cwx1 * (ay0 * cmp(Vq[i][1], c) + ay1 * cmp(Vq[i + 1][1], c));
            }
            f3* op = (f3*)(out + obase + (size_t)s * splane);
            f3 v; v.x = a[0]; v.y = a[1]; v.z = a[2];
            *op = v;
        }
    }
}

} // namespace

extern "C" void kernel_launch(void* const* d_in, const int* in_sizes, int n_in,
                              void* d_out, int out_size, void* d_ws, size_t ws_size,
                              hipStream_t stream) {
    const float* xs = (const float*)d_in[0];
    float* out = (float*)d_out;
    dim3 grid(GX * GY, B, R);
    fused_shift_rotate_lds4<<<grid, dim3(256), 0, stream>>>(xs, out);
}

// Round 5
// 242.100 us; speedup vs baseline: 1.0582x; 1.0036x over previous
//
#include <hip/hip_runtime.h>

namespace {

constexpr int H = 224, W = 224, B = 4, S = 21, R = 5;
constexpr int HW = H * W;            // 50176

constexpr int TW = 32, TH = 8;       // output tile per block (256 threads)
constexpr int GX = W / TW;           // 7
constexpr int GY = H / TH;           // 28
constexpr int WINW = 40, WINH = 32;  // staged source window (fit proof: see r2/r3)
constexpr int LSTR = 41;             // float4 row stride: 164 dwords == 4 (mod 32)
constexpr int NPX = WINW * WINH;     // 1280 staged pixels; LDS = 32*41*16 B = 20.5 KiB

__constant__ float c_sin[5] = {-0.5000010604f, -0.2588196365f, 0.0f,
                                0.2588196365f,  0.5000010604f};
__constant__ float c_cos[5] = { 0.8660247916f,  0.9659256678f, 1.0f,
                                0.9659256678f,  0.8660247916f};

struct alignas(4) f3 { float x, y, z; };   // 12 B global-side pixel

__device__ __forceinline__ float vIn(int x) {   // H == W
    return ((unsigned)x < (unsigned)W) ? 1.0f : 0.0f;
}
__device__ __forceinline__ float cmp(const float4& v, int c) {  // folded under unroll
    return c == 0 ? v.x : (c == 1 ? v.y : v.z);
}

// One block = 32x8 output tile for fixed (b, r); all 21 shifts from a float4 LDS window.
// Register diet: pre-blend rows (x-group) / cols (y-group) once -> 24-float tiles.
__global__ __launch_bounds__(256, 4) void fused_shift_rotate_blend(
    const float* __restrict__ xs, float* __restrict__ out) {
    __shared__ float4 lds4[WINH][LSTR];
    const int tid = threadIdx.x;
    const int tile = blockIdx.x;
    const int tx0 = (tile % GX) * TW;
    const int ty0 = (tile / GX) * TH;
    const int b = blockIdx.y;
    const int r = blockIdx.z;

    const float sr = c_sin[r], cr = c_cos[r];
    const float cx = 0.5f * (W - 1);

    // ---- uniform source-window origin from tile-corner extremes
    const float dxs = (float)tx0 - cx, dxe = (float)(tx0 + TW - 1) - cx;
    const float dys = (float)ty0 - cx, dye = (float)(ty0 + TH - 1) - cx;
    const float ixmin = cx + dxs * cr + fminf(dys * sr, dye * sr);
    const float iymin = cx + fminf(-dxs * sr, -dxe * sr) + dys * cr;
    const int cmin = min(max((int)floorf(ixmin) - 3, 0), W - WINW);
    const int rmin = min(max((int)floorf(iymin) - 3, 0), H - WINH);

    // ---- stage window: coalesced f3 global reads -> one ds_write_b128 per pixel
    const float* img = xs + (size_t)b * (HW * 3);
    const float* gsrc = img + rmin * (W * 3) + cmin * 3;
    #pragma unroll
    for (int k = 0; k < NPX / 256; ++k) {   // 5 iterations
        int idx = tid + k * 256;
        int row = idx / WINW;               // magic-mul
        int col = idx - row * WINW;
        const f3 t = *(const f3*)(gsrc + row * (W * 3) + col * 3);
        lds4[row][col] = make_float4(t.x, t.y, t.z, 0.0f);
    }
    __syncthreads();

    // ---- per-thread rotation geometry (identical math to proven kernel)
    const int wpx = tx0 + (tid & (TW - 1));
    const int hpx = ty0 + (tid >> 5);
    const float dx = (float)wpx - cx;
    const float dy = (float)hpx - cx;
    const float ix = fmaf(dy, sr, fmaf(dx, cr, cx));
    const float iy = fmaf(dy, cr, fmaf(-dx, sr, cx));

    const float x0f = floorf(ix), y0f = floorf(iy);
    const int x0 = (int)x0f, y0 = (int)y0f;
    const float wx = ix - x0f, wy = iy - y0f;
    const float wxl = 1.0f - wx, wyl = 1.0f - wy;

    const float vx0 = vIn(x0), vx1 = vIn(x0 + 1);
    const float vy0 = vIn(y0), vy1 = vIn(y0 + 1);
    const float rwy0 = wyl * vy0, rwy1 = wy * vy1;   // stage-2 y weights (masked)
    const float cwx0 = wxl * vx0, cwx1 = wx * vx1;   // stage-2 x weights (masked)

    const int pix = hpx * W + wpx;
    size_t obase = ((size_t)(r * S) * B + b) * (size_t)(HW * 3) + (size_t)pix * 3;
    constexpr size_t splane = (size_t)B * HW * 3;    // +1 in s

    auto lcol = [&](int g) { int l = g - cmin; return min(max(l, 0), WINW - 1); };
    auto lrow = [&](int g) { int l = g - rmin; return min(max(l, 0), WINH - 1); };

    const int xc0 = lcol(x0), xc1 = lcol(x0 + 1);

    // ---- x-shift group (s = 10..20): pre-blend rows y0/y0+1 once.
    // Rb[j][c] = rwy0*H[0][j][c] + rwy1*H[1][j][c]  (exact distributive rearrangement)
    {
        float Rb[8][3];
        const int R0 = lrow(y0), R1 = lrow(y0 + 1);
        #pragma unroll
        for (int j = 0; j < 8; ++j) {
            int xc = lcol(x0 - 3 + j);
            const float4 t0 = lds4[R0][xc];
            const float4 t1 = lds4[R1][xc];
            #pragma unroll
            for (int c = 0; c < 3; ++c)
                Rb[j][c] = rwy0 * cmp(t0, c) + rwy1 * cmp(t1, c);
        }
        constexpr int tx_tab[11] = {1, 2, 3, 4, 5, -1, -2, -3, -4, -5, 0};
        #pragma unroll
        for (int k = 0; k < 11; ++k) {
            const int tx = tx_tab[k];
            const int s = 10 + k;
            float a[3];
            if (tx & 1) {
                const int j = ((tx - 1) >> 1) + 3;       // compile-time
                int xb = x0 + ((tx - 1) >> 1);
                float cw0 = 0.5f * wxl * vx0 * vIn(xb);
                float cw1 = 0.5f * (wxl * vx0 + wx * vx1) * vIn(xb + 1);
                float cw2 = 0.5f * wx * vx1 * vIn(xb + 2);
                #pragma unroll
                for (int c = 0; c < 3; ++c)
                    a[c] = cw0 * Rb[j][c] + cw1 * Rb[j + 1][c] + cw2 * Rb[j + 2][c];
            } else {
                const int sx = tx >> 1;
                const int j = sx + 3;                    // compile-time
                float ax0 = cwx0 * vIn(x0 + sx);
                float ax1 = cwx1 * vIn(x0 + 1 + sx);
                #pragma unroll
                for (int c = 0; c < 3; ++c)
                    a[c] = ax0 * Rb[j][c] + ax1 * Rb[j + 1][c];
            }
            f3* op = (f3*)(out + obase + (size_t)s * splane);
            f3 v; v.x = a[0]; v.y = a[1]; v.z = a[2];
            *op = v;
        }
    }

    // ---- y-shift group (s = 0..9): pre-blend cols x0/x0+1 once.
    // Cb[i][c] = cwx0*V[i][0][c] + cwx1*V[i][1][c]
    {
        float Cb[8][3];
        #pragma unroll
        for (int i = 0; i < 8; ++i) {
            const int RR = lrow(y0 - 3 + i);
            const float4 t0 = lds4[RR][xc0];
            const float4 t1 = lds4[RR][xc1];
            #pragma unroll
            for (int c = 0; c < 3; ++c)
                Cb[i][c] = cwx0 * cmp(t0, c) + cwx1 * cmp(t1, c);
        }
        constexpr int ty_tab[10] = {1, 2, 3, 4, 5, -1, -2, -3, -4, -5};
        #pragma unroll
        for (int k = 0; k < 10; ++k) {
            const int ty = ty_tab[k];
            const int s = k;
            float a[3];
            if (ty & 1) {
                const int i = ((ty - 1) >> 1) + 3;       // compile-time
                int yb = y0 + ((ty - 1) >> 1);
                float rw0 = 0.5f * wyl * vy0 * vIn(yb);
                float rw1 = 0.5f * (wyl * vy0 + wy * vy1) * vIn(yb + 1);
                float rw2 = 0.5f * wy * vy1 * vIn(yb + 2);
                #pragma unroll
                for (int c = 0; c < 3; ++c)
                    a[c] = rw0 * Cb[i][c] + rw1 * Cb[i + 1][c] + rw2 * Cb[i + 2][c];
            } else {
                const int sy = ty >> 1;
                const int i = sy + 3;                    // compile-time
                float ay0 = rwy0 * vIn(y0 + sy);
                float ay1 = rwy1 * vIn(y0 + 1 + sy);
                #pragma unroll
                for (int c = 0; c < 3; ++c)
                    a[c] = ay0 * Cb[i][c] + ay1 * Cb[i + 1][c];
            }
            f3* op = (f3*)(out + obase + (size_t)s * splane);
            f3 v; v.x = a[0]; v.y = a[1]; v.z = a[2];
            *op = v;
        }
    }
}

} // namespace

extern "C" void kernel_launch(void* const* d_in, const int* in_sizes, int n_in,
                              void* d_out, int out_size, void* d_ws, size_t ws_size,
                              hipStream_t stream) {
    const float* xs = (const float*)d_in[0];
    float* out = (float*)d_out;
    dim3 grid(GX * GY, B, R);
    fused_shift_rotate_blend<<<grid, dim3(256), 0, stream>>>(xs, out);
}